// Round 21
// baseline (75.873 us; speedup 1.0000x reference)
//
#include <hip/hip_runtime.h>

#define D 128
#define TILE_N 16      // gemm: 16 nodes/tile; wave q = 16 nodes x 32 cols
#define RNODES 256     // nodes per range
#define FCAP 48        // pass-1 per-(range,block) segment slots
#define LCAP 32        // per-node bucket slots
#define SPILL_MAX 8192

typedef __attribute__((ext_vector_type(8))) short  short8;
typedef __attribute__((ext_vector_type(4))) float  f32x4;

__device__ inline unsigned short f32_to_bf16(float f) {
    unsigned int u = __float_as_uint(f);
    unsigned int r = (u + 0x7FFFu + ((u >> 16) & 1u)) >> 16;   // RNE
    return (unsigned short)r;
}
__device__ inline float bf16_to_f32(unsigned short s) {
    return __uint_as_float(((unsigned int)s) << 16);
}
__device__ inline short8 pack_bf16x8(float4 a, float4 b) {
    short8 u;
    u[0] = (short)f32_to_bf16(a.x); u[1] = (short)f32_to_bf16(a.y);
    u[2] = (short)f32_to_bf16(a.z); u[3] = (short)f32_to_bf16(a.w);
    u[4] = (short)f32_to_bf16(b.x); u[5] = (short)f32_to_bf16(b.y);
    u[6] = (short)f32_to_bf16(b.z); u[7] = (short)f32_to_bf16(b.w);
    return u;
}

__global__ __launch_bounds__(256) void zero_kernel(int* __restrict__ p, int n)
{
    int i = blockIdx.x * 256 + threadIdx.x;
    if (i < n) p[i] = 0;
}

// ---- prepbin: blocks [0,n_ranges) bin edge chunks; rest convert W ----------
__global__ __launch_bounds__(256) void prepbin_kernel(
    const float* __restrict__ W, unsigned short* __restrict__ Wb,
    const int* __restrict__ src, const int* __restrict__ dst,
    int n_edges, int chunk, int n_ranges,
    unsigned int* __restrict__ seg, int* __restrict__ cnt_grid,
    int* __restrict__ spill_cnt, int* __restrict__ spill)
{
    __shared__ __align__(16) char smem[50176];
    const int t = threadIdx.x;

    if ((int)blockIdx.x < n_ranges) {
        int* s_fcnt = (int*)smem;                              // 1KB
        unsigned int* s_fifo = (unsigned int*)(smem + 1024);   // 48KB
        const int b  = blockIdx.x;
        const int nb = n_ranges;

        for (int i = t; i < n_ranges; i += 256) s_fcnt[i] = 0;
        __syncthreads();

        const int e0 = b * chunk;
        const int e1 = (e0 + chunk < n_edges) ? e0 + chunk : n_edges;
        for (int i = e0 + t; i < e1; i += 256) {
            int dd = dst[i];
            int ss = src[i];
            int r  = dd >> 8;
            int pos = atomicAdd(&s_fcnt[r], 1);
            if (pos < FCAP) {
                s_fifo[r * FCAP + pos] = ((unsigned)dd << 16) | (unsigned)ss;
            } else {
                int k = atomicAdd(spill_cnt, 1);
                if (k < SPILL_MAX) { spill[2 * k] = dd; spill[2 * k + 1] = ss; }
            }
        }
        __syncthreads();

        for (int f = t; f < n_ranges * FCAP; f += 256) {
            int r = f / FCAP, slot = f - r * FCAP;
            if (slot < s_fcnt[r])
                seg[((size_t)r * nb + b) * FCAP + slot] = s_fifo[f];
        }
        for (int r = t; r < n_ranges; r += 256) {
            int c = s_fcnt[r];
            cnt_grid[r * nb + b] = (c > FCAP) ? FCAP : c;
        }
    } else {
        const int bid = blockIdx.x - n_ranges;
        const int tid = bid * 256 + t;
        if (tid < (D * D) / 8) {
            float4 v0 = *(const float4*)&W[tid * 8];
            float4 v1 = *(const float4*)&W[tid * 8 + 4];
            *(short8*)&Wb[tid * 8] = pack_bf16x8(v0, v1);
        }
    }
}

// ---- MEGA: blocks [0,n_ranges) = pass2; rest = PERSISTENT gemm blocks ------
// gemm role: grid-stride over tiles (grid sized so all blocks co-resident),
// no LDS/barrier, permuted-h direct store: pos 32q+2fr+k <-> col 32q+16k+fr.
__global__ __launch_bounds__(256, 8) void mega_kernel(
    const float* __restrict__ x, const unsigned short* __restrict__ Wb,
    const float* __restrict__ bias, const float* __restrict__ mask_u,
    unsigned short* __restrict__ h, int n_nodes, int n_tiles,
    const unsigned int* __restrict__ seg, const int* __restrict__ cnt_grid,
    int nb1, int n_ranges,
    int* __restrict__ deg, unsigned short* __restrict__ bucket,
    int* __restrict__ spill_cnt, int* __restrict__ spill)
{
    __shared__ __align__(16) char smem[19712];
    const int t = threadIdx.x;

    if ((int)blockIdx.x < n_ranges) {
        // -------- pass2: per-node binning for range r --------
        int* s_pref = (int*)smem;                         // 1KB
        int* s_cnt  = (int*)(smem + 1024);                // 1KB
        int* s_ncnt = (int*)(smem + 2048);                // 1KB
        unsigned short* s_slots = (unsigned short*)(smem + 3072);  // 16KB
        const int r = blockIdx.x;
        const unsigned rbase = (unsigned)r << 8;

        int v = (t < nb1) ? cnt_grid[r * nb1 + t] : 0;
        s_pref[t] = v;
        s_cnt[t]  = v;
        s_ncnt[t] = 0;
        __syncthreads();
        for (int o = 1; o < 256; o <<= 1) {
            int add = (t >= o) ? s_pref[t - o] : 0;
            __syncthreads();
            s_pref[t] += add;
            __syncthreads();
        }
        const int total = s_pref[255];

        for (int f = t; f < total; f += 256) {
            int lo = 0, hi = nb1 - 1;                 // first b: s_pref[b] > f
            while (lo < hi) {
                int mid = (lo + hi) >> 1;
                if (s_pref[mid] > f) hi = mid; else lo = mid + 1;
            }
            int slot = f - (s_pref[lo] - s_cnt[lo]);
            unsigned pk = seg[((size_t)r * nb1 + lo) * FCAP + slot];
            unsigned dd = pk >> 16;
            unsigned ss = pk & 0xFFFFu;
            int rel = (int)(dd - rbase);
            int pos = atomicAdd(&s_ncnt[rel], 1);
            if (pos < LCAP) {
                s_slots[(rel << 5) + pos] = (unsigned short)ss;
            } else {
                int k = atomicAdd(spill_cnt, 1);
                if (k < SPILL_MAX) { spill[2 * k] = (int)dd; spill[2 * k + 1] = (int)ss; }
            }
        }
        __syncthreads();

        const int node = (int)rbase + t;
        if (node < n_nodes) {
            int c = s_ncnt[t];
            deg[node] = (c > LCAP) ? LCAP : c;
        }
        for (int vv = t; vv < 1024; vv += 256) {     // 256 nodes x 4 short8
            int rel = vv >> 2;
            int gn  = (int)rbase + rel;
            if (gn < n_nodes)
                *(short8*)&bucket[((size_t)gn << 5) + ((vv & 3) << 3)] =
                    *(const short8*)&s_slots[vv << 3];
        }
    } else {
        // -------- persistent gemm role --------
        const int lane = t & 63;
        const int q    = t >> 6;      // col quarter
        const int fr   = lane & 15;
        const int fg   = lane >> 4;

        // loop-invariant: bias, Wb row pointers
        const float bs0 = bias[32 * q + fr];
        const float bs1 = bias[32 * q + 16 + fr];
        const unsigned short* wb0 = Wb + (size_t)(32 * q + fr) * D;
        const unsigned short* wb1 = Wb + (size_t)(32 * q + 16 + fr) * D;
        unsigned int* h32 = (unsigned int*)h;
        const int gstride = gridDim.x - n_ranges;

        for (int tile = blockIdx.x - n_ranges; tile < n_tiles; tile += gstride) {
            const int n0 = tile * TILE_N;

            // issue-early: mask scalars (clamped rows)
            float mk0[4], mk1[4];
            #pragma unroll
            for (int r = 0; r < 4; ++r) {
                int nr = n0 + fg * 4 + r;
                if (nr >= n_nodes) nr = n_nodes - 1;
                const size_t mo = (size_t)nr * D + 32 * q + fr;
                mk0[r] = mask_u[mo];
                mk1[r] = mask_u[mo + 16];
            }

            // issue-early: x fragments (f32, pack in-register)
            int arow = n0 + fr;
            if (arow >= n_nodes) arow = n_nodes - 1;
            const float* xr = x + (size_t)arow * D;
            short8 a0 = pack_bf16x8(*(const float4*)&xr[ 0 + fg * 8],
                                    *(const float4*)&xr[ 4 + fg * 8]);
            short8 a1 = pack_bf16x8(*(const float4*)&xr[32 + fg * 8],
                                    *(const float4*)&xr[36 + fg * 8]);
            short8 a2 = pack_bf16x8(*(const float4*)&xr[64 + fg * 8],
                                    *(const float4*)&xr[68 + fg * 8]);
            short8 a3 = pack_bf16x8(*(const float4*)&xr[96 + fg * 8],
                                    *(const float4*)&xr[100 + fg * 8]);

            f32x4 acc0 = (f32x4){0.f, 0.f, 0.f, 0.f};
            f32x4 acc1 = (f32x4){0.f, 0.f, 0.f, 0.f};
            #pragma unroll
            for (int s = 0; s < 4; ++s) {
                short8 a = (s == 0) ? a0 : (s == 1) ? a1 : (s == 2) ? a2 : a3;
                short8 b0 = *(const short8*)&wb0[s * 32 + fg * 8];
                short8 b1 = *(const short8*)&wb1[s * 32 + fg * 8];
                acc0 = __builtin_amdgcn_mfma_f32_16x16x32_bf16(a, b0, acc0, 0, 0, 0);
                acc1 = __builtin_amdgcn_mfma_f32_16x16x32_bf16(a, b1, acc1, 0, 0, 0);
            }

            // bias+relu+dropout, pack pair, direct store (permuted layout)
            #pragma unroll
            for (int r = 0; r < 4; ++r) {
                const int nr = n0 + fg * 4 + r;
                if (nr < n_nodes) {
                    float v0 = fmaxf(acc0[r] + bs0, 0.f) * (mk0[r] >= 0.5f ? 2.f : 0.f);
                    float v1 = fmaxf(acc1[r] + bs1, 0.f) * (mk1[r] >= 0.5f ? 2.f : 0.f);
                    unsigned u = (unsigned)f32_to_bf16(v0) |
                                 ((unsigned)f32_to_bf16(v1) << 16);
                    h32[(size_t)nr * 64 + q * 16 + fr] = u;
                }
            }
        }
    }
}

// ---- Gather-reduce (permuted h; inverse-permute on out store) --------------
__global__ __launch_bounds__(256) void gather_reduce_kernel(
    const unsigned short* __restrict__ h, const int* __restrict__ deg,
    const unsigned short* __restrict__ bucket, float* __restrict__ out,
    int n_nodes, const int* __restrict__ spill_cnt, const int* __restrict__ spill)
{
    const int t = threadIdx.x;
    const int node = blockIdx.x * 16 + (t >> 4);
    if (node >= n_nodes) return;
    const int l16 = t & 15;
    const int cb = l16 * 8;
    int dg = deg[node];
    if (dg > LCAP) dg = LCAP;
    const unsigned short* b = bucket + ((size_t)node << 5);

    float acc[8];
    #pragma unroll
    for (int j = 0; j < 8; ++j) acc[j] = 0.f;

    int i = 0;
    for (; i + 7 < dg; i += 8) {     // 8-deep: loads in flight (L3-bound)
        short8 v0 = *(const short8*)&h[(size_t)b[i]     * D + cb];
        short8 v1 = *(const short8*)&h[(size_t)b[i + 1] * D + cb];
        short8 v2 = *(const short8*)&h[(size_t)b[i + 2] * D + cb];
        short8 v3 = *(const short8*)&h[(size_t)b[i + 3] * D + cb];
        short8 v4 = *(const short8*)&h[(size_t)b[i + 4] * D + cb];
        short8 v5 = *(const short8*)&h[(size_t)b[i + 5] * D + cb];
        short8 v6 = *(const short8*)&h[(size_t)b[i + 6] * D + cb];
        short8 v7 = *(const short8*)&h[(size_t)b[i + 7] * D + cb];
        #pragma unroll
        for (int j = 0; j < 8; ++j)
            acc[j] += ((bf16_to_f32((unsigned short)v0[j]) +
                        bf16_to_f32((unsigned short)v1[j])) +
                       (bf16_to_f32((unsigned short)v2[j]) +
                        bf16_to_f32((unsigned short)v3[j]))) +
                      ((bf16_to_f32((unsigned short)v4[j]) +
                        bf16_to_f32((unsigned short)v5[j])) +
                       (bf16_to_f32((unsigned short)v6[j]) +
                        bf16_to_f32((unsigned short)v7[j])));
    }
    for (; i + 3 < dg; i += 4) {
        short8 v0 = *(const short8*)&h[(size_t)b[i]     * D + cb];
        short8 v1 = *(const short8*)&h[(size_t)b[i + 1] * D + cb];
        short8 v2 = *(const short8*)&h[(size_t)b[i + 2] * D + cb];
        short8 v3 = *(const short8*)&h[(size_t)b[i + 3] * D + cb];
        #pragma unroll
        for (int j = 0; j < 8; ++j)
            acc[j] += (bf16_to_f32((unsigned short)v0[j]) +
                       bf16_to_f32((unsigned short)v1[j])) +
                      (bf16_to_f32((unsigned short)v2[j]) +
                       bf16_to_f32((unsigned short)v3[j]));
    }
    for (; i < dg; ++i) {
        short8 v0 = *(const short8*)&h[(size_t)b[i] * D + cb];
        #pragma unroll
        for (int j = 0; j < 8; ++j) acc[j] += bf16_to_f32((unsigned short)v0[j]);
    }

    int nsp = *spill_cnt;
    if (nsp > 0) {
        if (nsp > SPILL_MAX) nsp = SPILL_MAX;
        for (int e = 0; e < nsp; ++e) {
            if (spill[2 * e] == node) {
                int ss = spill[2 * e + 1];
                short8 v = *(const short8*)&h[(size_t)ss * D + cb];
                #pragma unroll
                for (int j = 0; j < 8; ++j)
                    acc[j] += bf16_to_f32((unsigned short)v[j]);
            }
        }
    }

    // inverse permutation: even j -> col 32q+f0+j/2 ; odd j -> 32q+16+f0+j/2
    const int q  = l16 >> 2;
    const int f0 = 4 * (l16 & 3);
    f32x4 s1 = (f32x4){acc[0], acc[2], acc[4], acc[6]};
    f32x4 s2 = (f32x4){acc[1], acc[3], acc[5], acc[7]};
    __builtin_nontemporal_store(s1, (f32x4*)&out[(size_t)node * D + 32 * q + f0]);
    __builtin_nontemporal_store(s2, (f32x4*)&out[(size_t)node * D + 32 * q + 16 + f0]);
}

// ---- fallback path (ws too small or n_nodes > 65535) -----------------------
__global__ __launch_bounds__(256) void gemm_fb_kernel(
    const float* __restrict__ x, const float* __restrict__ W,
    const float* __restrict__ bias, const float* __restrict__ mask_u,
    unsigned short* __restrict__ h, int n_nodes)
{
    int tid = blockIdx.x * 256 + threadIdx.x;
    if (tid >= n_nodes * 16) return;
    int node = tid >> 4, cg = tid & 15;
    for (int c = 0; c < 8; ++c) {
        int col = cg * 8 + c;
        float s = bias[col];
        for (int k = 0; k < D; ++k)
            s += bf16_to_f32(f32_to_bf16(x[(size_t)node * D + k])) *
                 bf16_to_f32(f32_to_bf16(W[(size_t)col * D + k]));
        s = fmaxf(s, 0.f);
        float m = mask_u[(size_t)node * D + col];
        s *= (m >= 0.5f) ? 2.f : 0.f;
        h[(size_t)node * D + col] = f32_to_bf16(s);
    }
}

__global__ __launch_bounds__(256) void scatter_atomic_kernel(
    const unsigned short* __restrict__ h, const int* __restrict__ src,
    const int* __restrict__ dst, float* __restrict__ out, int n_edges)
{
    const int t = threadIdx.x;
    const int e = blockIdx.x * 16 + (t >> 4);
    if (e >= n_edges) return;
    const int cb = (t & 15) * 8;
    const int s  = src[e];
    const int dd = dst[e];
    short8 v = *(const short8*)&h[(size_t)s * D + cb];
    float* o = &out[(size_t)dd * D + cb];
    #pragma unroll
    for (int j = 0; j < 8; ++j) atomicAdd(o + j, bf16_to_f32((unsigned short)v[j]));
}

extern "C" void kernel_launch(void* const* d_in, const int* in_sizes, int n_in,
                              void* d_out, int out_size, void* d_ws, size_t ws_size,
                              hipStream_t stream) {
    const float* x      = (const float*)d_in[0];
    const float* W      = (const float*)d_in[1];
    const float* bias   = (const float*)d_in[2];
    const float* mask_u = (const float*)d_in[3];
    const int*   src    = (const int*)d_in[4];
    const int*   dst    = (const int*)d_in[5];
    float* out = (float*)d_out;

    const int n_nodes  = in_sizes[0] / D;
    const int n_edges  = in_sizes[4];
    const int n_tiles  = (n_nodes + TILE_N - 1) / TILE_N;
    const int n_ranges = (n_nodes + RNODES - 1) / RNODES;   // <= 256
    const int nb1      = n_ranges;
    const int chunk    = (n_edges + nb1 - 1) / nb1;

    // persistent gemm grid: total co-resident (8 blocks/CU x 256 CU = 2048)
    int gemm_blocks = 2048 - n_ranges;
    if (gemm_blocks > n_tiles) gemm_blocks = n_tiles;
    if (gemm_blocks < 1) gemm_blocks = 1;

    // ws: [Wb][h][deg][spill_cnt pad][spill][bucket][seg][cnt_grid]
    const size_t wb_bytes = (size_t)D * D * sizeof(unsigned short);
    const size_t h_bytes  = (size_t)n_nodes * D * sizeof(unsigned short);
    char* p = (char*)d_ws;
    unsigned short* Wb = (unsigned short*)p;     p += wb_bytes;
    unsigned short* h  = (unsigned short*)p;     p += h_bytes;
    int* deg       = (int*)p;                    p += (size_t)((n_nodes + 3) & ~3) * sizeof(int);
    int* spill_cnt = (int*)p;                    p += 16;
    int* spill     = (int*)p;                    p += (size_t)2 * SPILL_MAX * sizeof(int);
    unsigned short* bucket = (unsigned short*)p; p += (size_t)n_nodes * LCAP * sizeof(unsigned short);
    unsigned int* seg      = (unsigned int*)p;   p += (size_t)n_ranges * nb1 * FCAP * sizeof(unsigned int);
    int* cnt_grid  = (int*)p;                    p += (size_t)n_ranges * nb1 * sizeof(int);
    const size_t needed = (size_t)(p - (char*)d_ws);

    if (ws_size >= needed && n_nodes <= 65535) {
        zero_kernel<<<1, 256, 0, stream>>>(spill_cnt, 4);
        prepbin_kernel<<<n_ranges + 64, 256, 0, stream>>>(
            W, Wb, src, dst, n_edges, chunk, n_ranges,
            seg, cnt_grid, spill_cnt, spill);
        mega_kernel<<<n_ranges + gemm_blocks, 256, 0, stream>>>(
            x, Wb, bias, mask_u, h, n_nodes, n_tiles,
            seg, cnt_grid, nb1, n_ranges, deg, bucket, spill_cnt, spill);
        gather_reduce_kernel<<<(n_nodes + 15) / 16, 256, 0, stream>>>(
            h, deg, bucket, out, n_nodes, spill_cnt, spill);
    } else {
        unsigned short* hf = (unsigned short*)d_ws;   // only h fits
        gemm_fb_kernel<<<(n_nodes * 16 + 255) / 256, 256, 0, stream>>>(
            x, W, bias, mask_u, hf, n_nodes);
        zero_kernel<<<(out_size + 255) / 256, 256, 0, stream>>>((int*)d_out, out_size);
        scatter_atomic_kernel<<<(n_edges + 15) / 16, 256, 0, stream>>>(
            hf, src, dst, out, n_edges);
    }
}

// Round 22
// 73.224 us; speedup vs baseline: 1.0362x; 1.0362x over previous
//
#include <hip/hip_runtime.h>

#define D 128
#define TILE_N 16      // gemm: 16 nodes/block; wave q = 16 nodes x 32 cols
#define RNODES 256     // nodes per range
#define FCAP 48        // pass-1 per-(range,block) segment slots
#define LCAP 32        // per-node bucket slots
#define SPILL_MAX 8192

typedef __attribute__((ext_vector_type(8))) short  short8;
typedef __attribute__((ext_vector_type(4))) float  f32x4;

__device__ inline unsigned short f32_to_bf16(float f) {
    unsigned int u = __float_as_uint(f);
    unsigned int r = (u + 0x7FFFu + ((u >> 16) & 1u)) >> 16;   // RNE
    return (unsigned short)r;
}
__device__ inline float bf16_to_f32(unsigned short s) {
    return __uint_as_float(((unsigned int)s) << 16);
}
__device__ inline short8 pack_bf16x8(float4 a, float4 b) {
    short8 u;
    u[0] = (short)f32_to_bf16(a.x); u[1] = (short)f32_to_bf16(a.y);
    u[2] = (short)f32_to_bf16(a.z); u[3] = (short)f32_to_bf16(a.w);
    u[4] = (short)f32_to_bf16(b.x); u[5] = (short)f32_to_bf16(b.y);
    u[6] = (short)f32_to_bf16(b.z); u[7] = (short)f32_to_bf16(b.w);
    return u;
}

// ---- init: zero spill_cnt + convert W -> bf16 (was a wasted 1-block launch)
__global__ __launch_bounds__(256) void init_kernel(
    const float* __restrict__ W, unsigned short* __restrict__ Wb,
    int* __restrict__ spill_cnt)
{
    const int tid = blockIdx.x * 256 + threadIdx.x;
    if (tid < (D * D) / 8) {
        float4 v0 = *(const float4*)&W[tid * 8];
        float4 v1 = *(const float4*)&W[tid * 8 + 4];
        *(short8*)&Wb[tid * 8] = pack_bf16x8(v0, v1);
    }
    if (tid == 0) *spill_cnt = 0;
}

__global__ __launch_bounds__(256) void zero_kernel(int* __restrict__ p, int n)
{
    int i = blockIdx.x * 256 + threadIdx.x;
    if (i < n) p[i] = 0;
}

// ---- prepbin: pure binning, block b bins its edge chunk into range FIFOs ---
__global__ __launch_bounds__(256) void prepbin_kernel(
    const int* __restrict__ src, const int* __restrict__ dst,
    int n_edges, int chunk, int n_ranges,
    unsigned int* __restrict__ seg, int* __restrict__ cnt_grid,
    int* __restrict__ spill_cnt, int* __restrict__ spill)
{
    __shared__ int s_fcnt[RNODES];                    // n_ranges <= 256
    __shared__ unsigned int s_fifo[RNODES * FCAP];    // 48KB
    const int b  = blockIdx.x;
    const int t  = threadIdx.x;
    const int nb = gridDim.x;

    for (int i = t; i < n_ranges; i += 256) s_fcnt[i] = 0;
    __syncthreads();

    const int e0 = b * chunk;
    const int e1 = (e0 + chunk < n_edges) ? e0 + chunk : n_edges;
    for (int i = e0 + t; i < e1; i += 256) {
        int dd = dst[i];
        int ss = src[i];
        int r  = dd >> 8;
        int pos = atomicAdd(&s_fcnt[r], 1);
        if (pos < FCAP) {
            s_fifo[r * FCAP + pos] = ((unsigned)dd << 16) | (unsigned)ss;
        } else {
            int k = atomicAdd(spill_cnt, 1);
            if (k < SPILL_MAX) { spill[2 * k] = dd; spill[2 * k + 1] = ss; }
        }
    }
    __syncthreads();

    for (int f = t; f < n_ranges * FCAP; f += 256) {
        int r = f / FCAP, slot = f - r * FCAP;
        if (slot < s_fcnt[r])
            seg[((size_t)r * nb + b) * FCAP + slot] = s_fifo[f];
    }
    for (int r = t; r < n_ranges; r += 256) {
        int c = s_fcnt[r];
        cnt_grid[r * nb + b] = (c > FCAP) ? FCAP : c;
    }
}

// ---- MEGA: blocks [0,n_ranges) = pass2; rest = gemm tiles (round-20) -------
// gemm role: NO LDS, NO barrier. h stored in PERMUTED layout:
//   position p = 32q + 2*fr + k  <->  true col = 32q + 16k + fr
__global__ __launch_bounds__(256, 8) void mega_kernel(
    const float* __restrict__ x, const unsigned short* __restrict__ Wb,
    const float* __restrict__ bias, const float* __restrict__ mask_u,
    unsigned short* __restrict__ h, int n_nodes,
    const unsigned int* __restrict__ seg, const int* __restrict__ cnt_grid,
    int nb1, int n_ranges,
    int* __restrict__ deg, unsigned short* __restrict__ bucket,
    int* __restrict__ spill_cnt, int* __restrict__ spill)
{
    __shared__ __align__(16) char smem[19712];
    const int t = threadIdx.x;

    if ((int)blockIdx.x < n_ranges) {
        // -------- pass2: per-node binning for range r --------
        int* s_pref = (int*)smem;                         // 1KB
        int* s_cnt  = (int*)(smem + 1024);                // 1KB
        int* s_ncnt = (int*)(smem + 2048);                // 1KB
        unsigned short* s_slots = (unsigned short*)(smem + 3072);  // 16KB
        const int r = blockIdx.x;
        const unsigned rbase = (unsigned)r << 8;

        int v = (t < nb1) ? cnt_grid[r * nb1 + t] : 0;
        s_pref[t] = v;
        s_cnt[t]  = v;
        s_ncnt[t] = 0;
        __syncthreads();
        for (int o = 1; o < 256; o <<= 1) {
            int add = (t >= o) ? s_pref[t - o] : 0;
            __syncthreads();
            s_pref[t] += add;
            __syncthreads();
        }
        const int total = s_pref[255];

        for (int f = t; f < total; f += 256) {
            int lo = 0, hi = nb1 - 1;                 // first b: s_pref[b] > f
            while (lo < hi) {
                int mid = (lo + hi) >> 1;
                if (s_pref[mid] > f) hi = mid; else lo = mid + 1;
            }
            int slot = f - (s_pref[lo] - s_cnt[lo]);
            unsigned pk = seg[((size_t)r * nb1 + lo) * FCAP + slot];
            unsigned dd = pk >> 16;
            unsigned ss = pk & 0xFFFFu;
            int rel = (int)(dd - rbase);
            int pos = atomicAdd(&s_ncnt[rel], 1);
            if (pos < LCAP) {
                s_slots[(rel << 5) + pos] = (unsigned short)ss;
            } else {
                int k = atomicAdd(spill_cnt, 1);
                if (k < SPILL_MAX) { spill[2 * k] = (int)dd; spill[2 * k + 1] = (int)ss; }
            }
        }
        __syncthreads();

        const int node = (int)rbase + t;
        if (node < n_nodes) {
            int c = s_ncnt[t];
            deg[node] = (c > LCAP) ? LCAP : c;
        }
        for (int vv = t; vv < 1024; vv += 256) {     // 256 nodes x 4 short8
            int rel = vv >> 2;
            int gn  = (int)rbase + rel;
            if (gn < n_nodes)
                *(short8*)&bucket[((size_t)gn << 5) + ((vv & 3) << 3)] =
                    *(const short8*)&s_slots[vv << 3];
        }
    } else {
        // -------- gemm tile role: direct permuted h store, no LDS/barrier ---
        const int lane = t & 63;
        const int q    = t >> 6;      // col quarter
        const int fr   = lane & 15;
        const int fg   = lane >> 4;
        const int n0 = (blockIdx.x - n_ranges) * TILE_N;

        // issue-early: mask scalars for this lane's 8 outputs (clamped rows)
        float mk0[4], mk1[4];
        #pragma unroll
        for (int r = 0; r < 4; ++r) {
            int nr = n0 + fg * 4 + r;
            if (nr >= n_nodes) nr = n_nodes - 1;
            const size_t mo = (size_t)nr * D + 32 * q + fr;
            mk0[r] = mask_u[mo];
            mk1[r] = mask_u[mo + 16];
        }

        // issue-early: x fragments (f32, pack in-register)
        int arow = n0 + fr;
        if (arow >= n_nodes) arow = n_nodes - 1;
        const float* xr = x + (size_t)arow * D;
        short8 a0 = pack_bf16x8(*(const float4*)&xr[ 0 + fg * 8],
                                *(const float4*)&xr[ 4 + fg * 8]);
        short8 a1 = pack_bf16x8(*(const float4*)&xr[32 + fg * 8],
                                *(const float4*)&xr[36 + fg * 8]);
        short8 a2 = pack_bf16x8(*(const float4*)&xr[64 + fg * 8],
                                *(const float4*)&xr[68 + fg * 8]);
        short8 a3 = pack_bf16x8(*(const float4*)&xr[96 + fg * 8],
                                *(const float4*)&xr[100 + fg * 8]);

        const float bs0 = bias[32 * q + fr];
        const float bs1 = bias[32 * q + 16 + fr];
        const unsigned short* wb0 = Wb + (size_t)(32 * q + fr) * D;
        const unsigned short* wb1 = Wb + (size_t)(32 * q + 16 + fr) * D;

        f32x4 acc0 = (f32x4){0.f, 0.f, 0.f, 0.f};
        f32x4 acc1 = (f32x4){0.f, 0.f, 0.f, 0.f};
        #pragma unroll
        for (int s = 0; s < 4; ++s) {
            short8 a = (s == 0) ? a0 : (s == 1) ? a1 : (s == 2) ? a2 : a3;
            short8 b0 = *(const short8*)&wb0[s * 32 + fg * 8];
            short8 b1 = *(const short8*)&wb1[s * 32 + fg * 8];
            acc0 = __builtin_amdgcn_mfma_f32_16x16x32_bf16(a, b0, acc0, 0, 0, 0);
            acc1 = __builtin_amdgcn_mfma_f32_16x16x32_bf16(a, b1, acc1, 0, 0, 0);
        }

        // bias+relu+dropout, pack pair, direct store (permuted layout)
        unsigned int* h32 = (unsigned int*)h;
        #pragma unroll
        for (int r = 0; r < 4; ++r) {
            const int nr = n0 + fg * 4 + r;
            if (nr < n_nodes) {
                float v0 = fmaxf(acc0[r] + bs0, 0.f) * (mk0[r] >= 0.5f ? 2.f : 0.f);
                float v1 = fmaxf(acc1[r] + bs1, 0.f) * (mk1[r] >= 0.5f ? 2.f : 0.f);
                unsigned u = (unsigned)f32_to_bf16(v0) |
                             ((unsigned)f32_to_bf16(v1) << 16);
                h32[(size_t)nr * 64 + q * 16 + fr] = u;
            }
        }
    }
}

// ---- Gather-reduce (permuted h; inverse-permute on out store) --------------
__global__ __launch_bounds__(256) void gather_reduce_kernel(
    const unsigned short* __restrict__ h, const int* __restrict__ deg,
    const unsigned short* __restrict__ bucket, float* __restrict__ out,
    int n_nodes, const int* __restrict__ spill_cnt, const int* __restrict__ spill)
{
    const int t = threadIdx.x;
    const int node = blockIdx.x * 16 + (t >> 4);
    if (node >= n_nodes) return;
    const int l16 = t & 15;
    const int cb = l16 * 8;
    int dg = deg[node];
    if (dg > LCAP) dg = LCAP;
    const unsigned short* b = bucket + ((size_t)node << 5);

    float acc[8];
    #pragma unroll
    for (int j = 0; j < 8; ++j) acc[j] = 0.f;

    int i = 0;
    for (; i + 7 < dg; i += 8) {     // 8-deep: loads in flight (L3-bound)
        short8 v0 = *(const short8*)&h[(size_t)b[i]     * D + cb];
        short8 v1 = *(const short8*)&h[(size_t)b[i + 1] * D + cb];
        short8 v2 = *(const short8*)&h[(size_t)b[i + 2] * D + cb];
        short8 v3 = *(const short8*)&h[(size_t)b[i + 3] * D + cb];
        short8 v4 = *(const short8*)&h[(size_t)b[i + 4] * D + cb];
        short8 v5 = *(const short8*)&h[(size_t)b[i + 5] * D + cb];
        short8 v6 = *(const short8*)&h[(size_t)b[i + 6] * D + cb];
        short8 v7 = *(const short8*)&h[(size_t)b[i + 7] * D + cb];
        #pragma unroll
        for (int j = 0; j < 8; ++j)
            acc[j] += ((bf16_to_f32((unsigned short)v0[j]) +
                        bf16_to_f32((unsigned short)v1[j])) +
                       (bf16_to_f32((unsigned short)v2[j]) +
                        bf16_to_f32((unsigned short)v3[j]))) +
                      ((bf16_to_f32((unsigned short)v4[j]) +
                        bf16_to_f32((unsigned short)v5[j])) +
                       (bf16_to_f32((unsigned short)v6[j]) +
                        bf16_to_f32((unsigned short)v7[j])));
    }
    for (; i + 3 < dg; i += 4) {
        short8 v0 = *(const short8*)&h[(size_t)b[i]     * D + cb];
        short8 v1 = *(const short8*)&h[(size_t)b[i + 1] * D + cb];
        short8 v2 = *(const short8*)&h[(size_t)b[i + 2] * D + cb];
        short8 v3 = *(const short8*)&h[(size_t)b[i + 3] * D + cb];
        #pragma unroll
        for (int j = 0; j < 8; ++j)
            acc[j] += (bf16_to_f32((unsigned short)v0[j]) +
                       bf16_to_f32((unsigned short)v1[j])) +
                      (bf16_to_f32((unsigned short)v2[j]) +
                       bf16_to_f32((unsigned short)v3[j]));
    }
    for (; i < dg; ++i) {
        short8 v0 = *(const short8*)&h[(size_t)b[i] * D + cb];
        #pragma unroll
        for (int j = 0; j < 8; ++j) acc[j] += bf16_to_f32((unsigned short)v0[j]);
    }

    int nsp = *spill_cnt;
    if (nsp > 0) {
        if (nsp > SPILL_MAX) nsp = SPILL_MAX;
        for (int e = 0; e < nsp; ++e) {
            if (spill[2 * e] == node) {
                int ss = spill[2 * e + 1];
                short8 v = *(const short8*)&h[(size_t)ss * D + cb];
                #pragma unroll
                for (int j = 0; j < 8; ++j)
                    acc[j] += bf16_to_f32((unsigned short)v[j]);
            }
        }
    }

    // inverse permutation: even j -> col 32q+f0+j/2 ; odd j -> 32q+16+f0+j/2
    const int q  = l16 >> 2;
    const int f0 = 4 * (l16 & 3);
    f32x4 s1 = (f32x4){acc[0], acc[2], acc[4], acc[6]};
    f32x4 s2 = (f32x4){acc[1], acc[3], acc[5], acc[7]};
    __builtin_nontemporal_store(s1, (f32x4*)&out[(size_t)node * D + 32 * q + f0]);
    __builtin_nontemporal_store(s2, (f32x4*)&out[(size_t)node * D + 32 * q + 16 + f0]);
}

// ---- fallback path (ws too small or n_nodes > 65535) -----------------------
__global__ __launch_bounds__(256) void gemm_fb_kernel(
    const float* __restrict__ x, const float* __restrict__ W,
    const float* __restrict__ bias, const float* __restrict__ mask_u,
    unsigned short* __restrict__ h, int n_nodes)
{
    int tid = blockIdx.x * 256 + threadIdx.x;
    if (tid >= n_nodes * 16) return;
    int node = tid >> 4, cg = tid & 15;
    for (int c = 0; c < 8; ++c) {
        int col = cg * 8 + c;
        float s = bias[col];
        for (int k = 0; k < D; ++k)
            s += bf16_to_f32(f32_to_bf16(x[(size_t)node * D + k])) *
                 bf16_to_f32(f32_to_bf16(W[(size_t)col * D + k]));
        s = fmaxf(s, 0.f);
        float m = mask_u[(size_t)node * D + col];
        s *= (m >= 0.5f) ? 2.f : 0.f;
        h[(size_t)node * D + col] = f32_to_bf16(s);
    }
}

__global__ __launch_bounds__(256) void scatter_atomic_kernel(
    const unsigned short* __restrict__ h, const int* __restrict__ src,
    const int* __restrict__ dst, float* __restrict__ out, int n_edges)
{
    const int t = threadIdx.x;
    const int e = blockIdx.x * 16 + (t >> 4);
    if (e >= n_edges) return;
    const int cb = (t & 15) * 8;
    const int s  = src[e];
    const int dd = dst[e];
    short8 v = *(const short8*)&h[(size_t)s * D + cb];
    float* o = &out[(size_t)dd * D + cb];
    #pragma unroll
    for (int j = 0; j < 8; ++j) atomicAdd(o + j, bf16_to_f32((unsigned short)v[j]));
}

extern "C" void kernel_launch(void* const* d_in, const int* in_sizes, int n_in,
                              void* d_out, int out_size, void* d_ws, size_t ws_size,
                              hipStream_t stream) {
    const float* x      = (const float*)d_in[0];
    const float* W      = (const float*)d_in[1];
    const float* bias   = (const float*)d_in[2];
    const float* mask_u = (const float*)d_in[3];
    const int*   src    = (const int*)d_in[4];
    const int*   dst    = (const int*)d_in[5];
    float* out = (float*)d_out;

    const int n_nodes  = in_sizes[0] / D;
    const int n_edges  = in_sizes[4];
    const int n_tiles  = (n_nodes + TILE_N - 1) / TILE_N;
    const int n_ranges = (n_nodes + RNODES - 1) / RNODES;   // <= 256
    const int nb1      = n_ranges;
    const int chunk    = (n_edges + nb1 - 1) / nb1;

    // ws: [Wb][h][deg][spill_cnt pad][spill][bucket][seg][cnt_grid]
    const size_t wb_bytes = (size_t)D * D * sizeof(unsigned short);
    const size_t h_bytes  = (size_t)n_nodes * D * sizeof(unsigned short);
    char* p = (char*)d_ws;
    unsigned short* Wb = (unsigned short*)p;     p += wb_bytes;
    unsigned short* h  = (unsigned short*)p;     p += h_bytes;
    int* deg       = (int*)p;                    p += (size_t)((n_nodes + 3) & ~3) * sizeof(int);
    int* spill_cnt = (int*)p;                    p += 16;
    int* spill     = (int*)p;                    p += (size_t)2 * SPILL_MAX * sizeof(int);
    unsigned short* bucket = (unsigned short*)p; p += (size_t)n_nodes * LCAP * sizeof(unsigned short);
    unsigned int* seg      = (unsigned int*)p;   p += (size_t)n_ranges * nb1 * FCAP * sizeof(unsigned int);
    int* cnt_grid  = (int*)p;                    p += (size_t)n_ranges * nb1 * sizeof(int);
    const size_t needed = (size_t)(p - (char*)d_ws);

    if (ws_size >= needed && n_nodes <= 65535) {
        init_kernel<<<(D * D / 8 + 255) / 256, 256, 0, stream>>>(W, Wb, spill_cnt);
        prepbin_kernel<<<n_ranges, 256, 0, stream>>>(
            src, dst, n_edges, chunk, n_ranges,
            seg, cnt_grid, spill_cnt, spill);
        mega_kernel<<<n_ranges + n_tiles, 256, 0, stream>>>(
            x, Wb, bias, mask_u, h, n_nodes,
            seg, cnt_grid, nb1, n_ranges, deg, bucket, spill_cnt, spill);
        gather_reduce_kernel<<<(n_nodes + 15) / 16, 256, 0, stream>>>(
            h, deg, bucket, out, n_nodes, spill_cnt, spill);
    } else {
        unsigned short* hf = (unsigned short*)d_ws;   // only h fits
        gemm_fb_kernel<<<(n_nodes * 16 + 255) / 256, 256, 0, stream>>>(
            x, W, bias, mask_u, hf, n_nodes);
        zero_kernel<<<(out_size + 255) / 256, 256, 0, stream>>>((int*)d_out, out_size);
        scatter_atomic_kernel<<<(n_edges + 15) / 16, 256, 0, stream>>>(
            hf, src, dst, out, n_edges);
    }
}